// Round 1
// baseline (262.502 us; speedup 1.0000x reference)
//
#include <hip/hip_runtime.h>

// CondConv2d: B=16, CIN=128, COUT=128, H=W=56, E=4, K=3x3, pad=1, stride=1, fp32.
// Key algebraic opt: fold routing into weights (conv is linear in W):
//   Wm[b] = sum_e r[b,e] * W[e]  -> one conv per sample (4x FLOP reduction).

typedef float f4 __attribute__((ext_vector_type(4)));

#define CIN   128
#define COUT  128
#define HH    56
#define WW    56
#define SP    (HH*WW)      // 3136
#define KJ    (CIN*9)      // 1152  (j = ci*9 + kh*3 + kw)

// ---------------------------------------------------------------------------
// Phase 1: Wm[b][j][co] = sum_e r[b][e] * W[e][co][j]   (transpose to co-fastest)
// W source layout: [E][COUT][CIN][3][3] -> [e][co][j], j fastest.
// LDS tile transpose so global reads AND writes are coalesced.
// grid (36, 16) = (j-blocks of 32, b); block 256.
// ---------------------------------------------------------------------------
__global__ __launch_bounds__(256) void mix_kernel(const float* __restrict__ W,
                                                  const float* __restrict__ r,
                                                  float* __restrict__ Wm) {
    __shared__ float tile[128][33];     // [co][jl], +1 pad -> conflict-free transpose
    const int jb = blockIdx.x;
    const int b  = blockIdx.y;
    const int t  = threadIdx.x;
    const int j0 = jb * 32;
    const float r0 = r[b*4+0], r1 = r[b*4+1], r2 = r[b*4+2], r3 = r[b*4+3];

    #pragma unroll
    for (int i = 0; i < 16; ++i) {
        int s  = t + 256*i;             // 4096 elements: [co=128][jl=32]
        int co = s >> 5, jl = s & 31;
        size_t src = (size_t)co*KJ + j0 + jl;
        float acc = r0*W[src]
                  + r1*W[src + 147456]   // + e*COUT*KJ
                  + r2*W[src + 294912]
                  + r3*W[src + 442368];
        tile[co][jl] = acc;
    }
    __syncthreads();
    #pragma unroll
    for (int i = 0; i < 16; ++i) {
        int s  = t + 256*i;
        int jl = s >> 7, co = s & 127;
        Wm[((size_t)b*KJ + j0 + jl)*128 + co] = tile[co][jl];
    }
}

// ---------------------------------------------------------------------------
// Phase 2: direct conv, one block per (b, output row h).
// Block tile: all 128 co x 56 w (padded to 64). 256 threads.
// Thread t = cg*8 + wg: micro-tile 4 co x 8 w (co = 4*cg.., w = 8*wg..).
// K-loop: 16 chunks of 8 input channels; LDS stages x rows (halo, zero-pad)
// and the contiguous Wm slab for the chunk.
// ---------------------------------------------------------------------------
__global__ __launch_bounds__(256) void conv_kernel(const float* __restrict__ x,
                                                   const float* __restrict__ Wm,
                                                   float* __restrict__ out) {
    __shared__ __align__(16) float xs[8][3][68];     // [ci_l][row][wi], wi = w+1, zero-padded
    __shared__ __align__(16) float wlds[8][9][128];  // [ci_l][tap][co]  (36 KB, contiguous copy)

    const int h  = blockIdx.x;          // 56
    const int b  = blockIdx.y;          // 16
    const int t  = threadIdx.x;
    const int wg = t & 7;               // w-group: w0 = 8*wg  (wg==7 -> masked columns)
    const int cg = t >> 3;              // co-group: co = 4*cg + i
    const int w0 = wg * 8;
    const float* xb = x + (size_t)b * CIN * SP;

    float acc[4][8];
    #pragma unroll
    for (int i = 0; i < 4; ++i)
        #pragma unroll
        for (int q = 0; q < 8; ++q) acc[i][q] = 0.f;

    for (int cc = 0; cc < 16; ++cc) {
        if (cc) __syncthreads();

        // --- stage weights: 9216 contiguous floats (Wm is chunk-contiguous) ---
        const float* wsrc = Wm + ((size_t)b*KJ + cc*72)*128;
        float* wdst = &wlds[0][0][0];
        #pragma unroll
        for (int it = 0; it < 9; ++it) {
            int s = t*4 + it*1024;
            *(f4*)&wdst[s] = *(const f4*)&wsrc[s];
        }

        // --- stage x: 8 ci x 3 rows x 68 cols (halo + right pad zeroed) ---
        const int ci0 = cc * 8;
        for (int s = t; s < 8*3*68; s += 256) {
            int cil = s / 204;
            int rem = s - cil*204;
            int rr  = rem / 68;
            int wi  = rem - rr*68;
            int row = h - 1 + rr;
            int w   = wi - 1;
            float v = 0.f;
            if ((unsigned)row < 56u && (unsigned)w < 56u)
                v = xb[(size_t)(ci0 + cil)*SP + row*56 + w];
            xs[cil][rr][wi] = v;
        }
        __syncthreads();

        // --- compute: per ci, pull 12-wide x rows to regs, then 9 taps x 4co x 8w FMA ---
        #pragma unroll 2
        for (int cil = 0; cil < 8; ++cil) {
            float xr[3][12];
            #pragma unroll
            for (int rr = 0; rr < 3; ++rr) {
                f4 a0 = *(const f4*)&xs[cil][rr][w0];
                f4 a1 = *(const f4*)&xs[cil][rr][w0+4];
                f4 a2 = *(const f4*)&xs[cil][rr][w0+8];
                #pragma unroll
                for (int jj = 0; jj < 4; ++jj) {
                    xr[rr][jj]   = a0[jj];
                    xr[rr][4+jj] = a1[jj];
                    xr[rr][8+jj] = a2[jj];
                }
            }
            #pragma unroll
            for (int kh = 0; kh < 3; ++kh)
                #pragma unroll
                for (int kw = 0; kw < 3; ++kw) {
                    f4 wv = *(const f4*)&wlds[cil][kh*3+kw][cg*4];
                    #pragma unroll
                    for (int i = 0; i < 4; ++i)
                        #pragma unroll
                        for (int q = 0; q < 8; ++q)
                            acc[i][q] = fmaf(wv[i], xr[kh][q+kw], acc[i][q]);
                }
        }
    }

    // --- store: 4 co x 8 w as two float4 each (w0<=48 guarantees in-bounds) ---
    if (w0 < 56) {
        #pragma unroll
        for (int i = 0; i < 4; ++i) {
            int co = cg*4 + i;
            float* op = out + (((size_t)b*COUT + co)*HH + h)*WW + w0;
            f4 v0, v1;
            #pragma unroll
            for (int q = 0; q < 4; ++q) { v0[q] = acc[i][q]; v1[q] = acc[i][q+4]; }
            *(f4*)&op[0] = v0;
            *(f4*)&op[4] = v1;
        }
    }
}

extern "C" void kernel_launch(void* const* d_in, const int* in_sizes, int n_in,
                              void* d_out, int out_size, void* d_ws, size_t ws_size,
                              hipStream_t stream) {
    const float* x  = (const float*)d_in[0];   // [16,128,56,56]
    const float* r  = (const float*)d_in[1];   // [16,4]
    const float* W  = (const float*)d_in[2];   // [4,128,128,3,3]
    float* outp = (float*)d_out;               // [16,128,56,56]
    float* Wm   = (float*)d_ws;                // 2,359,296 floats = 9.4 MB scratch

    mix_kernel <<<dim3(36, 16), 256, 0, stream>>>(W, r, Wm);
    conv_kernel<<<dim3(56, 16), 256, 0, stream>>>(x, Wm, outp);
}

// Round 2
// 74.486 us; speedup vs baseline: 3.5242x; 3.5242x over previous
//
#include <hip/hip_runtime.h>

// CondConv2d B=16,CIN=COUT=128,H=W=56,E=4,3x3,pad=1 fp32 -> bf16 MFMA implicit GEMM.
// 1) Fold routing into weights (conv linear in W): Wm[b] = sum_e r[b,e] W[e].
// 2) Per sample: out[co][p] = sum_{ci,tap} Wm[co][ci,tap] * xpatch[ci,tap][p]
//    via v_mfma_f32_16x16x32_bf16, fp32 accumulate.

typedef float  f32x4 __attribute__((ext_vector_type(4)));
typedef short  s16x8 __attribute__((ext_vector_type(8)));
typedef short  s16x4 __attribute__((ext_vector_type(4)));
typedef unsigned short u16x4 __attribute__((ext_vector_type(4)));

#define CIN  128
#define COUT 128
#define HH   56
#define WW   56
#define SP   (HH*WW)          // 3136
#define KJ   (CIN*9)          // 1152
#define EW   147456           // per-expert weight elems = COUT*CIN*9
#define BW_  147456           // per-sample Wmix elems = 4 cc * 9 tap * 128 co * 32 ci_l
#define CIPAD 36              // LDS ci padding (b64-aligned, bank-uniform)

static __device__ __forceinline__ unsigned short f2bf(float f) {
    unsigned u = __builtin_bit_cast(unsigned, f);
    return (unsigned short)((u + 0x7FFFu + ((u >> 16) & 1u)) >> 16);
}

// ---------------------------------------------------------------------------
// Phase 1: Wmix[b][cc][tap][co][ci_l] (bf16) = sum_e r[b,e] * W[e][co][cc*32+ci_l][tap]
// grid (576,16) x 256 threads; out writes coalesced (ci_l fastest).
// ---------------------------------------------------------------------------
__global__ __launch_bounds__(256) void mix_kernel(const float* __restrict__ W,
                                                  const float* __restrict__ r,
                                                  unsigned short* __restrict__ Wmix) {
    const int b = blockIdx.y;
    int o = blockIdx.x * 256 + threadIdx.x;          // [0, 147456)
    int ci_l = o & 31;
    int o2   = o >> 5;
    int co   = o2 & 127;
    int o3   = o2 >> 7;                              // [0, 36)
    int tap  = o3 % 9;
    int cc   = o3 / 9;
    int ci   = cc * 32 + ci_l;
    size_t src = ((size_t)co * CIN + ci) * 9 + tap;
    float acc = r[b*4+0] * W[src]
              + r[b*4+1] * W[src + 1*EW]
              + r[b*4+2] * W[src + 2*EW]
              + r[b*4+3] * W[src + 3*EW];
    Wmix[(size_t)b * BW_ + o] = f2bf(acc);
}

// ---------------------------------------------------------------------------
// Phase 2: one block per (b, output row h). 4 waves: 2(co-half) x 2(px-half).
// Wave tile: 64 co x 32 px -> 4x2 MFMA frags, K-loop = 4 ci-chunks x 9 taps.
// A-frags: direct coalesced global loads from Wmix (16B/lane, L2-resident).
// B-frags: x staged in LDS as [row][col][ci] bf16 (ci-pad 36), 2x ds_read_b64.
// ---------------------------------------------------------------------------
__global__ __launch_bounds__(256) void conv_mfma(const float* __restrict__ x,
                                                 const unsigned short* __restrict__ Wmix,
                                                 float* __restrict__ out) {
    __shared__ unsigned short xs[3 * 66 * CIPAD];    // 14256 B

    const int h    = blockIdx.x;                     // 56
    const int b    = blockIdx.y;                     // 16
    const int t    = threadIdx.x;
    const int lane = t & 63;
    const int wid  = t >> 6;
    const int wm   = wid >> 1;                       // co half
    const int wn   = wid & 1;                        // px half
    const int l15  = lane & 15;
    const int kg   = lane >> 4;
    const float* xb = x + (size_t)b * CIN * SP;
    const unsigned short* wb = Wmix + (size_t)b * BW_;

    f32x4 acc[4][2];
    #pragma unroll
    for (int mf = 0; mf < 4; ++mf)
        #pragma unroll
        for (int nf = 0; nf < 2; ++nf) acc[mf][nf] = (f32x4)0.f;

    for (int cc = 0; cc < 4; ++cc) {
        if (cc) __syncthreads();

        // --- stage x chunk: 32 ci x 3 rows x 66 cols (halo, zero-padded), bf16 ---
        // slot s -> col fastest (coalesced global), 4 ci per thread (b64 LDS write)
        for (int s = t; s < 1584; s += 256) {
            int col  = s % 66;
            int rest = s / 66;
            int q    = rest & 7;                     // ci quad
            int rr   = rest >> 3;                    // 0..2
            int row  = h - 1 + rr;
            int w    = col - 1;
            u16x4 v = (u16x4)0;
            if ((unsigned)row < 56u && (unsigned)w < 56u) {
                const float* p = xb + (size_t)(cc*32 + q*4) * SP + row*56 + w;
                v[0] = f2bf(p[0]);
                v[1] = f2bf(p[SP]);
                v[2] = f2bf(p[2*SP]);
                v[3] = f2bf(p[3*SP]);
            }
            *(u16x4*)&xs[(rr*66 + col)*CIPAD + q*4] = v;
        }
        __syncthreads();

        // --- 9 taps: A from global (coalesced, cached), B from LDS ---
        const unsigned short* wcc = wb + cc * (9 * 4096);
        #pragma unroll
        for (int kh = 0; kh < 3; ++kh) {
            #pragma unroll
            for (int kw = 0; kw < 3; ++kw) {
                const int tap = kh*3 + kw;
                const unsigned short* wt = wcc + tap*4096 + (wm*64 + l15)*32 + kg*8;
                s16x8 a[4];
                #pragma unroll
                for (int mf = 0; mf < 4; ++mf)
                    a[mf] = *(const s16x8*)(wt + mf*512);
                s16x8 bf[2];
                #pragma unroll
                for (int nf = 0; nf < 2; ++nf) {
                    int col = wn*32 + nf*16 + l15 + kw;          // <= 65
                    const unsigned short* ps = &xs[(kh*66 + col)*CIPAD + kg*8];
                    s16x4 lo = *(const s16x4*)ps;
                    s16x4 hi = *(const s16x4*)(ps + 4);
                    bf[nf] = __builtin_shufflevector(lo, hi, 0,1,2,3,4,5,6,7);
                }
                #pragma unroll
                for (int mf = 0; mf < 4; ++mf)
                    #pragma unroll
                    for (int nf = 0; nf < 2; ++nf)
                        acc[mf][nf] = __builtin_amdgcn_mfma_f32_16x16x32_bf16(
                            a[mf], bf[nf], acc[mf][nf], 0, 0, 0);
            }
        }
    }

    // --- store: D layout col=lane&15 (px), row=(lane>>4)*4+reg (co) ---
    #pragma unroll
    for (int nf = 0; nf < 2; ++nf) {
        int wout = wn*32 + nf*16 + l15;
        if (wout < 56) {
            #pragma unroll
            for (int mf = 0; mf < 4; ++mf) {
                #pragma unroll
                for (int rg = 0; rg < 4; ++rg) {
                    int co = wm*64 + mf*16 + kg*4 + rg;
                    out[(((size_t)b*COUT + co)*HH + h)*WW + wout] = acc[mf][nf][rg];
                }
            }
        }
    }
}

extern "C" void kernel_launch(void* const* d_in, const int* in_sizes, int n_in,
                              void* d_out, int out_size, void* d_ws, size_t ws_size,
                              hipStream_t stream) {
    const float* x = (const float*)d_in[0];          // [16,128,56,56]
    const float* r = (const float*)d_in[1];          // [16,4]
    const float* W = (const float*)d_in[2];          // [4,128,128,3,3]
    float* outp = (float*)d_out;                     // [16,128,56,56]
    unsigned short* Wmix = (unsigned short*)d_ws;    // 16*147456 bf16 = 4.7 MB

    mix_kernel<<<dim3(576, 16), 256, 0, stream>>>(W, r, Wmix);
    conv_mfma <<<dim3(56, 16),  256, 0, stream>>>(x, Wmix, outp);
}